// Round 1
// baseline (1958.960 us; speedup 1.0000x reference)
//
#include <hip/hip_runtime.h>
#include <math.h>

#define N_ENT  150000
#define N_USR  60000
#define CDIM   64
#define NE     1000000
#define NNZV   1000000

// Full 64-lane wave sum (all lanes get the result).
__device__ __forceinline__ float wave_sum(float v) {
#pragma unroll
    for (int m = 32; m > 0; m >>= 1) v += __shfl_xor(v, m, 64);
    return v;
}

// One wave per edge, lane = channel.
// att[e] = (sum_c (h_c r_c)^2) * (sum_c (t_c r_c)^2)  == (||h*r|| * ||t*r||)^2
// segmax[head] = max over segment (att >= 0, so int-bit atomicMax with 0-init is exact).
__global__ __launch_bounds__(256) void k_att(
    const float* __restrict__ ent, const float* __restrict__ wt,
    const int* __restrict__ head, const int* __restrict__ tail,
    const int* __restrict__ etype,
    float* __restrict__ att, float* __restrict__ segmax)
{
    int w = (blockIdx.x * 256 + threadIdx.x) >> 6;
    int lane = threadIdx.x & 63;
    if (w >= NE) return;
    int h = head[w], t = tail[w];
    int rt = etype[w] - 1;
    if (rt < 0) rt = 8;          // JAX/np negative-index wrap: weight[-1] -> row 8
    float r  = wt[rt * CDIM + lane];
    float hv = ent[(size_t)h * CDIM + lane] * r;
    float tv = ent[(size_t)t * CDIM + lane] * r;
    float hn2 = wave_sum(hv * hv);
    float tn2 = wave_sum(tv * tv);
    if (lane == 0) {
        float a = hn2 * tn2;
        att[w] = a;
        atomicMax((int*)(segmax + h), __float_as_int(a));  // a >= 0
    }
}

// One thread per edge: e = exp(att - max); att <- e; segsum[head] += e.
__global__ __launch_bounds__(256) void k_expsum(
    const int* __restrict__ head, float* __restrict__ att,
    const float* __restrict__ segmax, float* __restrict__ segsum)
{
    int e = blockIdx.x * 256 + threadIdx.x;
    if (e >= NE) return;
    int h = head[e];
    float v = __expf(att[e] - segmax[h]);
    att[e] = v;
    atomicAdd(segsum + h, v);
}

// One wave per edge: ent_next[head] += (e/s) * t * r
__global__ __launch_bounds__(256) void k_edge_scatter(
    const float* __restrict__ ent, const float* __restrict__ wt,
    const int* __restrict__ head, const int* __restrict__ tail,
    const int* __restrict__ etype,
    const float* __restrict__ att, const float* __restrict__ segsum,
    float* __restrict__ ent_next)
{
    int w = (blockIdx.x * 256 + threadIdx.x) >> 6;
    int lane = threadIdx.x & 63;
    if (w >= NE) return;
    int h = head[w], t = tail[w];
    int rt = etype[w] - 1;
    if (rt < 0) rt = 8;
    float wgt = att[w] / segsum[h];
    float r  = wt[rt * CDIM + lane];
    float tv = ent[(size_t)t * CDIM + lane];
    atomicAdd(ent_next + (size_t)h * CDIM + lane, wgt * tv * r);
}

// One wave per nnz: ent_next[col] += val*usr[row];  usr_next[row] += val*ent[col]
__global__ __launch_bounds__(256) void k_inter(
    const float* __restrict__ ent_cur, const float* __restrict__ usr_cur,
    const int* __restrict__ rows, const int* __restrict__ cols,
    const float* __restrict__ vals,
    float* __restrict__ ent_next, float* __restrict__ usr_next)
{
    int w = (blockIdx.x * 256 + threadIdx.x) >> 6;
    int lane = threadIdx.x & 63;
    if (w >= NNZV) return;
    int rr = rows[w], cc = cols[w];
    float v = vals[w];
    float u = usr_cur[(size_t)rr * CDIM + lane];
    float e = ent_cur[(size_t)cc * CDIM + lane];
    atomicAdd(ent_next + (size_t)cc * CDIM + lane, v * u);
    atomicAdd(usr_next + (size_t)rr * CDIM + lane, v * e);
}

// One wave per row: y = x / max(||x||, 1e-12); x <- y (in place, becomes next hop's
// input); out += y (residual accumulation).
__global__ __launch_bounds__(256) void k_norm_acc(
    float* __restrict__ x, float* __restrict__ out, int nrows)
{
    int row = (blockIdx.x * 256 + threadIdx.x) >> 6;
    int lane = threadIdx.x & 63;
    if (row >= nrows) return;
    float v = x[(size_t)row * CDIM + lane];
    float s = wave_sum(v * v);
    float inv = 1.0f / fmaxf(sqrtf(s), 1e-12f);
    float y = v * inv;
    x[(size_t)row * CDIM + lane] = y;
    out[(size_t)row * CDIM + lane] += y;
}

extern "C" void kernel_launch(void* const* d_in, const int* in_sizes, int n_in,
                              void* d_out, int out_size, void* d_ws, size_t ws_size,
                              hipStream_t stream)
{
    const float* user_emb   = (const float*)d_in[0];  // [N_USR, C]
    const float* entity_emb = (const float*)d_in[1];  // [N_ENT, C]
    const float* wt         = (const float*)d_in[2];  // [9, C]
    const float* inter_vals = (const float*)d_in[3];  // [NNZ]
    const int*   edge_index = (const int*)d_in[4];    // [2, E]
    const int*   etype      = (const int*)d_in[5];    // [E]
    const int*   inter_rows = (const int*)d_in[6];    // [NNZ]
    const int*   inter_cols = (const int*)d_in[7];    // [NNZ]
    const int* head  = edge_index;
    const int* tailp = edge_index + NE;

    // Workspace layout (floats): total ~28.2M floats = ~113 MB
    float* ws    = (float*)d_ws;
    float* ent_a = ws;
    float* ent_b = ent_a + (size_t)N_ENT * CDIM;
    float* usr_a = ent_b + (size_t)N_ENT * CDIM;
    float* usr_b = usr_a + (size_t)N_USR * CDIM;
    float* att   = usr_b + (size_t)N_USR * CDIM;
    float* smax  = att + NE;
    float* ssum  = smax + N_ENT;

    float* out_ent = (float*)d_out;
    float* out_usr = out_ent + (size_t)N_ENT * CDIM;

    // Residual init: out = inputs (d_out is re-poisoned before every call).
    hipMemcpyAsync(out_ent, entity_emb, sizeof(float) * (size_t)N_ENT * CDIM,
                   hipMemcpyDeviceToDevice, stream);
    hipMemcpyAsync(out_usr, user_emb, sizeof(float) * (size_t)N_USR * CDIM,
                   hipMemcpyDeviceToDevice, stream);

    const float* ent_cur = entity_emb;
    const float* usr_cur = user_emb;
    float* ent_nx = ent_a;
    float* usr_nx = usr_a;

    for (int hop = 0; hop < 2; ++hop) {
        hipMemsetAsync(smax, 0, sizeof(float) * N_ENT, stream);
        hipMemsetAsync(ssum, 0, sizeof(float) * N_ENT, stream);
        hipMemsetAsync(ent_nx, 0, sizeof(float) * (size_t)N_ENT * CDIM, stream);
        hipMemsetAsync(usr_nx, 0, sizeof(float) * (size_t)N_USR * CDIM, stream);

        k_att<<<NE / 4, 256, 0, stream>>>(ent_cur, wt, head, tailp, etype, att, smax);
        k_expsum<<<(NE + 255) / 256, 256, 0, stream>>>(head, att, smax, ssum);
        k_edge_scatter<<<NE / 4, 256, 0, stream>>>(ent_cur, wt, head, tailp, etype,
                                                   att, ssum, ent_nx);
        k_inter<<<NNZV / 4, 256, 0, stream>>>(ent_cur, usr_cur, inter_rows, inter_cols,
                                              inter_vals, ent_nx, usr_nx);
        k_norm_acc<<<(N_ENT + 3) / 4, 256, 0, stream>>>(ent_nx, out_ent, N_ENT);
        k_norm_acc<<<(N_USR + 3) / 4, 256, 0, stream>>>(usr_nx, out_usr, N_USR);

        // Next hop reads the (in-place normalized) aggregates.
        ent_cur = ent_nx;
        usr_cur = usr_nx;
        ent_nx = ent_b;
        usr_nx = usr_b;
    }
}

// Round 3
// 1074.942 us; speedup vs baseline: 1.8224x; 1.8224x over previous
//
#include <hip/hip_runtime.h>
#include <math.h>

#define N_ENT  150000
#define N_USR  60000
#define CDIM   64
#define NE     1000000
#define NNZV   1000000
#define NTOT   (2 * N_ENT + N_USR)      // 360000 concatenated segment counters
#define TOTAL_ITEMS (NE + 2 * NNZV)     // 3000000 (scan sentinel)
#define SCAN_B ((NTOT + 1023) / 1024)   // 352 scan blocks

// Full 64-lane wave sum (all lanes get the result).
__device__ __forceinline__ float wave_sum(float v) {
#pragma unroll
    for (int m = 32; m > 0; m >>= 1) v += __shfl_xor(v, m, 64);
    return v;
}

// Block-wide exclusive scan (blockDim multiple of 64, <=1024). lds: >=16 ints.
__device__ __forceinline__ int block_excl_scan(int v, int* lds) {
    int lane = threadIdx.x & 63, wid = threadIdx.x >> 6;
    int incl = v;
#pragma unroll
    for (int o = 1; o < 64; o <<= 1) {
        int t = __shfl_up(incl, o, 64);
        if (lane >= o) incl += t;
    }
    if (lane == 63) lds[wid] = incl;
    __syncthreads();
    int nw = blockDim.x >> 6;
    if ((int)threadIdx.x < nw) {
        int s = lds[threadIdx.x];
        int si = s;
        for (int o = 1; o < nw; o <<= 1) {
            int t = __shfl_up(si, o, 64);
            if ((int)threadIdx.x >= o) si += t;
        }
        lds[threadIdx.x] = si - s;  // exclusive offset for this wave
    }
    __syncthreads();
    return incl - v + lds[wid];
}

__global__ __launch_bounds__(256) void k_zero(int* __restrict__ p, int n) {
    int i = blockIdx.x * 256 + threadIdx.x;
    if (i < n) p[i] = 0;
}

// ---- CSR build: histogram -> scan(start,cursor) -> scatter(cursor only) ----

__global__ __launch_bounds__(256) void k_hist(
    const int* __restrict__ head, const int* __restrict__ cols,
    const int* __restrict__ rows, int* __restrict__ cnt)
{
    int i = blockIdx.x * 256 + threadIdx.x;
    if (i >= NE) return;
    atomicAdd(cnt + head[i], 1);
    atomicAdd(cnt + N_ENT + cols[i], 1);
    atomicAdd(cnt + 2 * N_ENT + rows[i], 1);
}

__global__ __launch_bounds__(1024) void k_bsum(
    const int* __restrict__ cnt, int* __restrict__ bsum)
{
    __shared__ int lds[16];
    int i = blockIdx.x * 1024 + threadIdx.x;
    int v = (i < NTOT) ? cnt[i] : 0;
#pragma unroll
    for (int m = 32; m > 0; m >>= 1) v += __shfl_xor(v, m, 64);
    int lane = threadIdx.x & 63, wid = threadIdx.x >> 6;
    if (lane == 0) lds[wid] = v;
    __syncthreads();
    if (threadIdx.x == 0) {
        int s = 0;
        for (int k = 0; k < 16; ++k) s += lds[k];
        bsum[blockIdx.x] = s;
    }
}

__global__ __launch_bounds__(512) void k_scan_small(int* __restrict__ bsum)
{
    __shared__ int lds[16];
    int i = threadIdx.x;
    int v = (i < SCAN_B) ? bsum[i] : 0;
    int e = block_excl_scan(v, lds);
    if (i < SCAN_B) bsum[i] = e;
}

// start[i] = exclusive prefix (immutable afterwards); start[NTOT] = sentinel.
// cursor[i] = same value; ONLY cursor is mutated by k_scatter.
__global__ __launch_bounds__(1024) void k_scan_apply(
    const int* __restrict__ cnt, const int* __restrict__ bsum,
    int* __restrict__ start, int* __restrict__ cursor)
{
    __shared__ int lds[16];
    int i = blockIdx.x * 1024 + threadIdx.x;
    int v = (i < NTOT) ? cnt[i] : 0;
    int e = block_excl_scan(v, lds) + bsum[blockIdx.x];
    if (i < NTOT) { start[i] = e; cursor[i] = e; }
    else if (i == NTOT) { start[i] = TOTAL_ITEMS; }
}

// Scatter payloads into segment-sorted arrays. Mutates cursor only.
// Bounds guards: no write can escape its array even if cursor were corrupted.
__global__ __launch_bounds__(256) void k_scatter(
    const int* __restrict__ head, const int* __restrict__ tail,
    const int* __restrict__ etype,
    const int* __restrict__ rows, const int* __restrict__ cols,
    const float* __restrict__ vals,
    int* __restrict__ cursor,
    int* __restrict__ pk_h,                              // tail | rt<<18, by head
    int* __restrict__ row_c, float* __restrict__ val_c,  // by col
    int* __restrict__ col_r, float* __restrict__ val_r)  // by row
{
    int i = blockIdx.x * 256 + threadIdx.x;
    if (i >= NE) return;
    int rt = etype[i] - 1;
    if (rt < 0) rt = 8;                                  // weight[-1] -> row 8
    int p = atomicAdd(cursor + head[i], 1);
    if ((unsigned)p < (unsigned)NE) pk_h[p] = tail[i] | (rt << 18);
    int r = rows[i], c = cols[i];
    float v = vals[i];
    p = atomicAdd(cursor + N_ENT + c, 1) - NE;
    if ((unsigned)p < (unsigned)NNZV) { row_c[p] = r; val_c[p] = v; }
    p = atomicAdd(cursor + 2 * N_ENT + r, 1) - 2 * NE;
    if ((unsigned)p < (unsigned)NNZV) { col_r[p] = c; val_r[p] = v; }
}

// ---- Fused per-hop kernels (gathers read only immutable start[]) ---------

// One wave per entity: online-softmax edge aggregation + interaction gather
// + L2-normalize + residual. FIRST: out = own + y; else out += y.
template <bool FIRST, bool LAST>
__global__ __launch_bounds__(256) void k_entity(
    const float* __restrict__ ent_cur, const float* __restrict__ usr_cur,
    const float* __restrict__ wt, const int* __restrict__ start,
    const int* __restrict__ pk_h,
    const int* __restrict__ row_c, const float* __restrict__ val_c,
    float* __restrict__ ent_next, float* __restrict__ out_ent)
{
    int e = (blockIdx.x * 256 + threadIdx.x) >> 6;
    int lane = threadIdx.x & 63;
    if (e >= N_ENT) return;
    float own = ent_cur[(size_t)e * CDIM + lane];

    // softmax-weighted neighbor aggregation over edges with head == e
    int s1 = min(start[e + 1], NE);
    int s0 = min(start[e], s1);
    float m = 0.f, l = 0.f, acc = 0.f;   // att >= 0, so m=0 init is exact
    for (int j = s0; j < s1; ++j) {
        int pk = pk_h[j];
        int t = pk & 0x3FFFF, rt = (pk >> 18) & 15;
        float r  = wt[rt * CDIM + lane];
        float tr = ent_cur[(size_t)t * CDIM + lane] * r;   // neigh = t * rel
        float hv = own * r;
        float hn2 = wave_sum(hv * hv);
        float tn2 = wave_sum(tr * tr);
        float a = hn2 * tn2;                               // (||h*r||·||t*r||)^2
        float mn = fmaxf(m, a);
        float corr = __expf(m - mn);   // first iter multiplies zero accs
        float p = __expf(a - mn);
        l = l * corr + p;
        acc = acc * corr + p * tr;
        m = mn;
    }
    float agg = (l > 0.f) ? acc / l : 0.f;

    // + interact_mat^T @ user_emb  (nnz with col == e)
    int c1 = min(start[N_ENT + e + 1] - NE, NNZV);
    int c0 = max(min(start[N_ENT + e] - NE, c1), 0);
    for (int j = c0; j < c1; ++j) {
        int u = row_c[j];
        agg += val_c[j] * usr_cur[(size_t)u * CDIM + lane];
    }

    float s = wave_sum(agg * agg);
    float y = agg / fmaxf(sqrtf(s), 1e-12f);
    if (!LAST) ent_next[(size_t)e * CDIM + lane] = y;
    size_t oi = (size_t)e * CDIM + lane;
    if (FIRST) out_ent[oi] = own + y;
    else       out_ent[oi] += y;
}

// One wave per user: user_agg = sum val*ent[col]; normalize; residual.
template <bool FIRST, bool LAST>
__global__ __launch_bounds__(256) void k_user(
    const float* __restrict__ ent_cur, const float* __restrict__ usr_base,
    const int* __restrict__ start,
    const int* __restrict__ col_r, const float* __restrict__ val_r,
    float* __restrict__ usr_next, float* __restrict__ out_usr)
{
    int u = (blockIdx.x * 256 + threadIdx.x) >> 6;
    int lane = threadIdx.x & 63;
    if (u >= N_USR) return;
    int s1 = min(start[2 * N_ENT + u + 1] - 2 * NE, NNZV);
    int s0 = max(min(start[2 * N_ENT + u] - 2 * NE, s1), 0);
    float acc = 0.f;
    for (int j = s0; j < s1; ++j) {
        int c = col_r[j];
        acc += val_r[j] * ent_cur[(size_t)c * CDIM + lane];
    }
    float s = wave_sum(acc * acc);
    float y = acc / fmaxf(sqrtf(s), 1e-12f);
    if (!LAST) usr_next[(size_t)u * CDIM + lane] = y;
    size_t oi = (size_t)u * CDIM + lane;
    if (FIRST) out_usr[oi] = usr_base[oi] + y;
    else       out_usr[oi] += y;
}

extern "C" void kernel_launch(void* const* d_in, const int* in_sizes, int n_in,
                              void* d_out, int out_size, void* d_ws, size_t ws_size,
                              hipStream_t stream)
{
    const float* user_emb   = (const float*)d_in[0];
    const float* entity_emb = (const float*)d_in[1];
    const float* wt         = (const float*)d_in[2];
    const float* inter_vals = (const float*)d_in[3];
    const int*   edge_index = (const int*)d_in[4];
    const int*   etype      = (const int*)d_in[5];
    const int*   inter_rows = (const int*)d_in[6];
    const int*   inter_cols = (const int*)d_in[7];
    const int* head  = edge_index;
    const int* tailp = edge_index + NE;

    // Workspace layout (~77 MB), every buffer written before read each call
    float* ent_a  = (float*)d_ws;                          // N_ENT*64
    float* usr_a  = ent_a + (size_t)N_ENT * CDIM;          // N_USR*64
    int*   cnt    = (int*)(usr_a + (size_t)N_USR * CDIM);  // NTOT
    int*   start  = cnt + NTOT;                            // NTOT+1
    int*   cursor = start + NTOT + 1;                      // NTOT+1
    int*   pk_h   = cursor + NTOT + 1;                     // NE
    int*   row_c  = pk_h + NE;                             // NNZ
    float* val_c  = (float*)(row_c + NNZV);                // NNZ
    int*   col_r  = (int*)(val_c + NNZV);                  // NNZ
    float* val_r  = (float*)(col_r + NNZV);                // NNZ
    int*   bsum   = (int*)(val_r + NNZV);                  // SCAN_B

    float* out_ent = (float*)d_out;
    float* out_usr = out_ent + (size_t)N_ENT * CDIM;

    // ---- CSR build (indices are hop-invariant: once per call) ----
    k_zero<<<(NTOT + 255) / 256, 256, 0, stream>>>(cnt, NTOT);
    k_hist<<<(NE + 255) / 256, 256, 0, stream>>>(head, inter_cols, inter_rows, cnt);
    k_bsum<<<SCAN_B, 1024, 0, stream>>>(cnt, bsum);
    k_scan_small<<<1, 512, 0, stream>>>(bsum);
    k_scan_apply<<<SCAN_B, 1024, 0, stream>>>(cnt, bsum, start, cursor);
    k_scatter<<<(NE + 255) / 256, 256, 0, stream>>>(
        head, tailp, etype, inter_rows, inter_cols, inter_vals,
        cursor, pk_h, row_c, val_c, col_r, val_r);

    const int EG = N_ENT / 4;   // 4 waves per 256-thread block, exact
    const int UG = N_USR / 4;

    // ---- hop 1: read inputs, write ent_a/usr_a, out = input + y1 ----
    k_entity<true, false><<<EG, 256, 0, stream>>>(
        entity_emb, user_emb, wt, start, pk_h, row_c, val_c, ent_a, out_ent);
    k_user<true, false><<<UG, 256, 0, stream>>>(
        entity_emb, user_emb, start, col_r, val_r, usr_a, out_usr);

    // ---- hop 2: read ent_a/usr_a, out += y2 (no next buffers) ----
    k_entity<false, true><<<EG, 256, 0, stream>>>(
        ent_a, usr_a, wt, start, pk_h, row_c, val_c, nullptr, out_ent);
    k_user<false, true><<<UG, 256, 0, stream>>>(
        ent_a, nullptr, start, col_r, val_r, nullptr, out_usr);
}